// Round 1
// baseline (135.064 us; speedup 1.0000x reference)
//
#include <hip/hip_runtime.h>

#define HW 256
#define CH 64

// 256 threads = 4 waves; each wave handles 8 consecutive pixels as TWO
// depth-pipelined batches of 4 (16 lanes/pixel: lane%16 = channel quad,
// lane/16 = pixel-in-wave-batch).
// Pipeline: both batches' offset+mask chains issue together up front;
// batch-1 address broadcast overlaps batch-0 gather latency; batch-1
// gathers are issued inside the batch-0 FMA loop (register reuse keeps
// data VGPRs at 36); batch-0 reduce+store overlaps batch-1 gather wait.
__global__ __launch_bounds__(256, 8) void DeformableConvLayer_kernel(
    const float* __restrict__ inp,    // [4,256,256,64]
    const float* __restrict__ gt,     // [256,256]
    const float* __restrict__ off,    // [4,256,256,18]
    const float* __restrict__ ker,    // [9][64]
    const float* __restrict__ bias,   // [1]
    float* __restrict__ out)          // [4,256,256]
{
    __shared__ float wlds[576];       // 9 taps x 64 ch
    const int tid = threadIdx.x;
    if (tid < 144) ((float4*)wlds)[tid] = ((const float4*)ker)[tid];

    const int lane = tid & 63;
    const int wave = tid >> 6;
    const int q16  = lane & 48;       // pixel-in-batch * 16
    const int t    = lane & 15;       // channel quad

    // XCD swizzle: contiguous 1024-block chunk per XCD (8192 blocks total)
    const int bid = blockIdx.x;
    const int vb  = (bid & 7) * 1024 + (bid >> 3);

    // 32 consecutive pixels per block (never crosses a row: 256/32=8).
    const int p0 = vb * 32 + wave * 8 + (q16 >> 4);
    const int p1 = p0 + 4;
    const int b  = p0 >> 16;
    const int i  = (p0 >> 8) & 255;
    const int j0 = p0 & 255;
    const int j1 = j0 + 4;
    const float* inb = inp + (long)b * (HW * HW * CH);

    // ---- Phase 1: one tap per lane (t<9), BOTH batches ----
    int pack0 = -1, pack1 = -1;
    if (t < 9) {
        const int tap = t;
        const int ky = tap / 3, kx = tap - ky * 3;
        const int iy = i + ky - 1;

        // both offset loads issue back-to-back (independent)
        float2 oa = *(const float2*)(off + (long)p0 * 18 + 2 * tap);
        float2 ob = *(const float2*)(off + (long)p1 * 18 + 2 * tap);

        { // batch 0
            int ix = j0 + kx - 1;
            bool interior = (iy >= 0) & (iy < HW) & (ix >= 0) & (ix < HW);
            int yi = interior ? iy : 0;
            int xi = interior ? ix : 0;
            float p_mask = (yi >= 1 && xi >= 1) ? gt[(yi - 1) * HW + (xi - 1)] : 0.f;
            float yf = (float)yi, xf = (float)xi;
            float yof = fminf(fmaxf(floorf(yf + oa.x), 0.f), 257.f);
            float xof = fminf(fmaxf(floorf(xf + oa.y), 0.f), 257.f);
            int yo = (int)yof, xo = (int)xof;
            float p_mask_off = (yo >= 1 && yo <= HW && xo >= 1 && xo <= HW)
                               ? gt[(yo - 1) * HW + (xo - 1)] : 0.f;
            float diff = (p_mask != p_mask_off) ? 1.f : 0.f;
            float y = fminf(fmaxf(yf + oa.x * diff, 0.f), 255.f);
            float x = fminf(fmaxf(xf + oa.y * diff, 0.f), 255.f);
            int y0 = (int)y, x0 = (int)x;
            bool valid = (y0 >= 1) & (x0 >= 1);
            pack0 = valid ? ((y0 - 1) * HW + (x0 - 1)) * CH : -1;
        }
        { // batch 1 (same row, column +4)
            int ix = j1 + kx - 1;
            bool interior = (iy >= 0) & (iy < HW) & (ix >= 0) & (ix < HW);
            int yi = interior ? iy : 0;
            int xi = interior ? ix : 0;
            float p_mask = (yi >= 1 && xi >= 1) ? gt[(yi - 1) * HW + (xi - 1)] : 0.f;
            float yf = (float)yi, xf = (float)xi;
            float yof = fminf(fmaxf(floorf(yf + ob.x), 0.f), 257.f);
            float xof = fminf(fmaxf(floorf(xf + ob.y), 0.f), 257.f);
            int yo = (int)yof, xo = (int)xof;
            float p_mask_off = (yo >= 1 && yo <= HW && xo >= 1 && xo <= HW)
                               ? gt[(yo - 1) * HW + (xo - 1)] : 0.f;
            float diff = (p_mask != p_mask_off) ? 1.f : 0.f;
            float y = fminf(fmaxf(yf + ob.x * diff, 0.f), 255.f);
            float x = fminf(fmaxf(xf + ob.y * diff, 0.f), 255.f);
            int y0 = (int)y, x0 = (int)x;
            bool valid = (y0 >= 1) & (x0 >= 1);
            pack1 = valid ? ((y0 - 1) * HW + (x0 - 1)) * CH : -1;
        }
    }

    // ---- Phase 2a: broadcast batch-0 addresses ----
    int pk0[9];
    #pragma unroll
    for (int k = 0; k < 9; ++k) pk0[k] = __shfl(pack0, q16 + k);

    // ---- Phase 3a: batch-0 gathers (36 VGPRs in flight) ----
    float4 v[9];
    #pragma unroll
    for (int k = 0; k < 9; ++k) {
        int eo = pk0[k] >= 0 ? pk0[k] : 0;
        v[k] = *(const float4*)(inb + eo + t * 4);
    }
    int m0 = 0;
    #pragma unroll
    for (int k = 0; k < 9; ++k) m0 |= (int)(pk0[k] >= 0) << k;   // frees pk0

    // ---- Phase 2b: batch-1 broadcast (LDS ops hide under gather wait) ----
    int pk1[9];
    #pragma unroll
    for (int k = 0; k < 9; ++k) pk1[k] = __shfl(pack1, q16 + k);

    __syncthreads();                  // weights staged (also under gather wait)

    // ---- Phase 4a: batch-0 FMA fused with batch-1 gather issue ----
    float acc0 = 0.f;
    int m1 = 0;
    #pragma unroll
    for (int k = 0; k < 9; ++k) {
        float4 w = ((const float4*)wlds)[k * 16 + t];
        float d = v[k].x * w.x + v[k].y * w.y + v[k].z * w.z + v[k].w * w.w;
        acc0 += ((m0 >> k) & 1) ? d : 0.f;
        m1 |= (int)(pk1[k] >= 0) << k;
        int eo = pk1[k] >= 0 ? pk1[k] : 0;
        v[k] = *(const float4*)(inb + eo + t * 4);   // reuse v[k]
    }

    // batch-0 reduce + store overlap batch-1 gather latency
    acc0 += __shfl_xor(acc0, 8);
    acc0 += __shfl_xor(acc0, 4);
    acc0 += __shfl_xor(acc0, 2);
    acc0 += __shfl_xor(acc0, 1);
    if (t == 0) out[p0] = acc0 + bias[0];

    // ---- Phase 4b: batch-1 FMA + reduce ----
    float acc1 = 0.f;
    #pragma unroll
    for (int k = 0; k < 9; ++k) {
        float4 w = ((const float4*)wlds)[k * 16 + t];
        float d = v[k].x * w.x + v[k].y * w.y + v[k].z * w.z + v[k].w * w.w;
        acc1 += ((m1 >> k) & 1) ? d : 0.f;
    }
    acc1 += __shfl_xor(acc1, 8);
    acc1 += __shfl_xor(acc1, 4);
    acc1 += __shfl_xor(acc1, 2);
    acc1 += __shfl_xor(acc1, 1);
    if (t == 0) out[p1] = acc1 + bias[0];
}

extern "C" void kernel_launch(void* const* d_in, const int* in_sizes, int n_in,
                              void* d_out, int out_size, void* d_ws, size_t ws_size,
                              hipStream_t stream) {
    const float* inp  = (const float*)d_in[0];
    const float* gt   = (const float*)d_in[1];
    const float* off  = (const float*)d_in[2];
    const float* ker  = (const float*)d_in[3];
    const float* bias = (const float*)d_in[4];
    float* out = (float*)d_out;

    // 262144 pixels / 32 per block = 8192 blocks
    DeformableConvLayer_kernel<<<8192, 256, 0, stream>>>(inp, gt, off, ker, bias, out);
}